// Round 6
// baseline (47.104 us; speedup 1.0000x reference)
//
#include <hip/hip_runtime.h>

#define CLS 8
#define BATCH 8
#define BPB 64                       // blocks per batch -> 512 blocks, 4096 px/block
#define NSLICE 8
#define LOG2E 1.442695040888963f
#define LN2   0.693147180559945f

// select compile-time component e of a float4/int4
#define F4C(v, e) ((e) == 0 ? (v).x : (e) == 1 ? (v).y : (e) == 2 ? (v).z : (v).w)

struct WS {
    float    S[NSLICE][BATCH][64];   // class-conditional channel sums
    float    n[NSLICE][BATCH][CLS];  // class pixel counts
    float    lse[NSLICE];            // sum of log2(sum_i exp2(p_i*log2e))
    unsigned cnt;                    // completion ticket
};

__device__ __forceinline__ float wave_reduce(float v) {
#pragma unroll
    for (int off = 32; off > 0; off >>= 1) v += __shfl_xor(v, off);
    return v;
}

__global__ __launch_bounds__(256, 2) void jce_fused(
    const float* __restrict__ pred, const int* __restrict__ tgt,
    const float* __restrict__ w, float* __restrict__ out,
    WS* ws, int N)
{
    const int tid  = threadIdx.x;
    const int b    = blockIdx.x & (BATCH - 1);   // batch pinned to XCD (round-robin)
    const int blk  = blockIdx.x >> 3;            // 0..63
    const int base = blk * (N / BPB);            // 4096 px per block
    const float* pb = pred + (size_t)b * CLS * N;
    const int*   tb = tgt  + (size_t)b * N;

    float acc[64];                               // acc[i*8+k] = sum_{p: t=k} pred[i]
#pragma unroll
    for (int j = 0; j < 64; ++j) acc[j] = 0.f;
    float accl = 0.f;                            // sum log2(sum_i 2^(pc_i*log2e))
    int cls_cnt[CLS] = {0, 0, 0, 0, 0, 0, 0, 0}; // wave-uniform class counts

    // depth-3 float4 register pipeline: 27 loads (6.9KB/lane-slot) in flight
    float4 pA[CLS], pB[CLS], pC[CLS];
    int4 tA, tB, tC;

#define LOADG(P, T, g) do {                                                     \
        const int _pix = base + (g) * 1024 + tid * 4;                           \
        _Pragma("unroll")                                                       \
        for (int _i = 0; _i < CLS; ++_i)                                        \
            (P)[_i] = *reinterpret_cast<const float4*>(pb + (size_t)_i * N + _pix); \
        (T) = *reinterpret_cast<const int4*>(tb + _pix);                        \
    } while (0)

#define COMPUTE_E(P, T, e) do {                                                 \
        float _pc[CLS];                                                         \
        _Pragma("unroll")                                                       \
        for (int _i = 0; _i < CLS; ++_i) _pc[_i] = F4C((P)[_i], e);             \
        const int _t = F4C((T), e);                                             \
        float _s = 0.f;                                                         \
        _Pragma("unroll")                                                       \
        for (int _i = 0; _i < CLS; ++_i) _s += exp2f(_pc[_i] * LOG2E);          \
        accl += log2f(_s);                                                      \
        _Pragma("unroll")                                                       \
        for (int _k = 0; _k < CLS; ++_k) {                                      \
            const bool _isk = (_t == _k);                                       \
            cls_cnt[_k] += __popcll(__ballot(_isk));                            \
            const float _pm = _isk ? 1.f : 0.f;                                 \
            _Pragma("unroll")                                                   \
            for (int _i = 0; _i < CLS; ++_i)                                    \
                acc[_i * 8 + _k] = fmaf(_pm, _pc[_i], acc[_i * 8 + _k]);        \
        }                                                                       \
    } while (0)

#define COMPUTE4(P, T) do {                                                     \
        COMPUTE_E(P, T, 0); COMPUTE_E(P, T, 1);                                 \
        COMPUTE_E(P, T, 2); COMPUTE_E(P, T, 3);                                 \
    } while (0)

    LOADG(pA, tA, 0);
    LOADG(pB, tB, 1);
    LOADG(pC, tC, 2);      // 27 loads issued before any wait
    COMPUTE4(pA, tA);
    LOADG(pA, tA, 3);      // refill A; in flight during B and C compute
    COMPUTE4(pB, tB);
    COMPUTE4(pC, tC);
    COMPUTE4(pA, tA);

#undef LOADG
#undef COMPUTE_E
#undef COMPUTE4

    // split-vector butterfly: reduce the 64-entry register vector across 64 lanes;
    // lane l ends holding the wave-total of entry bitrev6(l)
    const int lane = tid & 63;
#pragma unroll
    for (int s6 = 0; s6 < 6; ++s6) {
        const int d = 1 << s6;
        const int half = 32 >> s6;
        const bool hi = (lane & d) != 0;
#pragma unroll
        for (int j = 0; j < half; ++j) {
            const float keep = hi ? acc[j + half] : acc[j];
            const float send = hi ? acc[j] : acc[j + half];
            acc[j] = keep + __shfl_xor(send, d);
        }
    }
    const int e = ((lane & 1) << 5) | ((lane & 2) << 3) | ((lane & 4) << 1) |
                  ((lane & 8) >> 1) | ((lane & 16) >> 3) | ((lane & 32) >> 5);

    __shared__ float redS[4][64];
    __shared__ float redl[4];
    __shared__ int   redc[4][CLS];
    const int wv = tid >> 6;

    redS[wv][e] = acc[0];
    const float lsum = wave_reduce(accl);
    if (lane == 0) {
        redl[wv] = lsum;
#pragma unroll
        for (int k = 0; k < CLS; ++k) redc[wv][k] = cls_cnt[k];
    }
    __syncthreads();

    const int sl = blk & (NSLICE - 1);
    if (tid < 64) {
        const float v = redS[0][tid] + redS[1][tid] + redS[2][tid] + redS[3][tid];
        atomicAdd(&ws->S[sl][b][tid], v);
    } else if (tid < 64 + CLS) {
        const int k = tid - 64;
        const float v = (float)(redc[0][k] + redc[1][k] + redc[2][k] + redc[3][k]);
        atomicAdd(&ws->n[sl][b][k], v);
    } else if (tid == 64 + CLS) {
        atomicAdd(&ws->lse[sl], redl[0] + redl[1] + redl[2] + redl[3]);
    }

    // ---- last-block-done epilogue (replaces second dispatch) ----
    __syncthreads();                 // drains this block's outstanding atomics (vmcnt 0)
    __shared__ int lastFlag;
    if (tid == 0) {
        __threadfence();
        const unsigned t = atomicAdd(&ws->cnt, 1u);
        lastFlag = (t == gridDim.x - 1) ? 1 : 0;
    }
    __syncthreads();
    if (!lastFlag) return;
    __threadfence();

    __shared__ float eS[BATCH][64];
    __shared__ float en[BATCH][CLS];
    __shared__ float eLse, eCe;

    // read accumulators via atomic (device-coherent across XCD L2s)
    for (int j = tid; j < 577; j += 256) {
        float s = 0.f;
        if (j < 512) {
            const int bb = j >> 6, ee = j & 63;
#pragma unroll
            for (int s8 = 0; s8 < NSLICE; ++s8) s += atomicAdd(&ws->S[s8][bb][ee], 0.f);
            eS[bb][ee] = s;
        } else if (j < 576) {
            const int q = j - 512, bb = q >> 3, k = q & 7;
#pragma unroll
            for (int s8 = 0; s8 < NSLICE; ++s8) s += atomicAdd(&ws->n[s8][bb][k], 0.f);
            en[bb][k] = s;
        } else {
#pragma unroll
            for (int s8 = 0; s8 < NSLICE; ++s8) s += atomicAdd(&ws->lse[s8], 0.f);
            eLse = s * LN2;          // natural-log LSE sum
        }
    }
    __syncthreads();

    // ce = (sum lse - sum_b trace(S_b)) / (B*N)   [picked = trace of unnormalized S]
    if (tid < 64) {
        const int bb = tid >> 3, k = tid & 7;
        float tv = eS[bb][k * 9];
        tv = wave_reduce(tv);
        if (tid == 0) eCe = (eLse - tv) / ((float)BATCH * (float)N);
    }
    __syncthreads();

    // j[b] = -sum_{i!=k} w[i,k]*log(0.5 + 0.5*(A[i,i]-A[i,k])); out = j + ce
    const int i = lane >> 3, k = lane & 7;
#pragma unroll
    for (int r = 0; r < 2; ++r) {
        const int bb = wv * 2 + r;           // 4 waves x 2 batches
        const float A    = eS[bb][lane] / en[bb][k];
        const float diag = eS[bb][i * 9] / en[bb][i];
        float term = 0.f;
        if (i != k)
            term = w[lane] * (log2f(0.5f + 0.5f * (diag - A)) * LN2);
        term = wave_reduce(term);
        if (lane == 0) out[bb] = -term + eCe;
    }
}

extern "C" void kernel_launch(void* const* d_in, const int* in_sizes, int n_in,
                              void* d_out, int out_size, void* d_ws, size_t ws_size,
                              hipStream_t stream) {
    const float* pred = (const float*)d_in[0];
    const int*   tgt  = (const int*)d_in[1];
    const float* w    = (const float*)d_in[2];
    float* out = (float*)d_out;

    const int N = in_sizes[1] / BATCH;        // H*W = 262144
    WS* ws = (WS*)d_ws;

    hipMemsetAsync(ws, 0, sizeof(WS), stream);
    jce_fused<<<dim3(BATCH * BPB), dim3(256), 0, stream>>>(pred, tgt, w, out, ws, N);
}